// Round 8
// baseline (274.004 us; speedup 1.0000x reference)
//
#include <hip/hip_runtime.h>
#include <math.h>

#define D 256
#define NX 16
#define L 2048
#define NBATCH 8
#define NTOK (NBATCH * L)
#define CL 32
#define NCH (L / CL)  // 64
#define LOG2E 1.44269504088896340736f

// ---------------- K0: A -> At[n][d] with LOG2E folded ----------------
__global__ __launch_bounds__(256) void k0_at(const float* __restrict__ A,
                                             float* __restrict__ At) {
  int i = blockIdx.x * 256 + threadIdx.x;  // 4096 total
  int d = i >> 4, n = i & 15;
  At[n * D + d] = A[i] * LOG2E;
}

// ---------------- K0b: [WB;WC] -> Wbct[d][c] (c: 0-15 B, 16-31 C) ----------
__global__ __launch_bounds__(256) void k0b_wbct(const float* __restrict__ WB,
                                                const float* __restrict__ WC,
                                                float* __restrict__ Wbct) {
  int i = blockIdx.x * 256 + threadIdx.x;  // 8192 total
  int d = i >> 5, c = i & 31;
  Wbct[i] = (c < 16) ? WB[c * D + d] : WC[(c - 16) * D + d];
}

// ---------------- K1: 32-token block front end (weight-amortized GEMM) ------
__global__ __launch_bounds__(256) void k1_front(
    const float* __restrict__ y, const float* __restrict__ Win,
    const float* __restrict__ bin_, const float* __restrict__ ng,
    const float* __restrict__ nb, const float* __restrict__ Wbct,
    const float* __restrict__ qd, const float* __restrict__ pd,
    float* __restrict__ hn, float* __restrict__ delta,
    float* __restrict__ Bm, float* __restrict__ Cm,
    float* __restrict__ muv, float* __restrict__ irsv) {
  __shared__ float sy[32][32];    // y tile (reads are wave-uniform broadcasts)
  __shared__ float sh[32][260];   // hn tile, pitch 260 -> phase-C conflict-free
  int t = threadIdx.x;
  int tok0 = blockIdx.x * 32;
  {
    const float4* src = (const float4*)(y + (size_t)tok0 * 32);
    ((float4*)sy)[t] = src[t];  // 1024 floats, fully coalesced
  }
  __syncthreads();
  int dcol = t & 63;          // lane; owns d = dcol*4..+3
  int jrow = t >> 6;          // wave id; wave owns tokens jrow*8..+7
  int d4 = dcol * 4;
  float4 bv = ((const float4*)bin_)[dcol];
  float4 acc[8];
  #pragma unroll
  for (int jj = 0; jj < 8; ++jj) acc[jj] = bv;
  const float4* Win4 = (const float4*)Win;  // [k][64 float4]
  #pragma unroll
  for (int k = 0; k < 32; ++k) {
    float4 wv = Win4[k * 64 + dcol];
    #pragma unroll
    for (int jj = 0; jj < 8; ++jj) {
      float av = sy[jrow * 8 + jj][k];  // wave-uniform broadcast
      acc[jj].x = fmaf(av, wv.x, acc[jj].x);
      acc[jj].y = fmaf(av, wv.y, acc[jj].y);
      acc[jj].z = fmaf(av, wv.z, acc[jj].z);
      acc[jj].w = fmaf(av, wv.w, acc[jj].w);
    }
  }
  // LN + delta per token, straight from registers
  float4 g4 = ((const float4*)ng)[dcol];
  float4 nb4 = ((const float4*)nb)[dcol];
  float4 q4 = ((const float4*)qd)[dcol];
  float pd0 = pd[0];
  #pragma unroll
  for (int jj = 0; jj < 8; ++jj) {
    int j = jrow * 8 + jj;
    int tok = tok0 + j;
    float4 a = acc[jj];
    float s1 = a.x + a.y + a.z + a.w;
    float s2 = a.x * a.x + a.y * a.y + a.z * a.z + a.w * a.w;
    #pragma unroll
    for (int off = 1; off < 64; off <<= 1) {
      s1 += __shfl_xor(s1, off);
      s2 += __shfl_xor(s2, off);
    }
    float mu = s1 * (1.f / D);
    float var = s2 * (1.f / D) - mu * mu;
    float rstd = rsqrtf(var + 1e-5f);
    if (dcol == 0) { muv[tok] = mu; irsv[tok] = sqrtf(var + 1e-5f); }
    float4 v4;
    v4.x = (a.x - mu) * rstd * g4.x + nb4.x;
    v4.y = (a.y - mu) * rstd * g4.y + nb4.y;
    v4.z = (a.z - mu) * rstd * g4.z + nb4.z;
    v4.w = (a.w - mu) * rstd * g4.w + nb4.w;
    ((float4*)(hn + (size_t)tok * D))[dcol] = v4;
    *(float4*)&sh[j][d4] = v4;
    float dd = v4.x * q4.x + v4.y * q4.y + v4.z * q4.z + v4.w * q4.w;
    #pragma unroll
    for (int off = 1; off < 64; off <<= 1) dd += __shfl_xor(dd, off);
    if (dcol == 0) {
      float xx = pd0 + dd;
      delta[tok] = (xx > 20.f) ? xx : log1pf(expf(xx));
    }
  }
  __syncthreads();
  // Phase C: [Bm|Cm](32 tok x 32 cols) = sh(32x256) @ Wbct(256x32)
  int col4 = t & 7;   // float4 column group (cols col4*4..+3)
  int j = t >> 3;     // token 0..31
  const float4* W4 = (const float4*)Wbct;  // [d][8 float4]
  float4 o = make_float4(0.f, 0.f, 0.f, 0.f);
  #pragma unroll 8
  for (int d = 0; d < 256; ++d) {
    float av = sh[j][d];          // 8 j's/wave, banks 4j%32 offset -> no conflict
    float4 w = W4[d * 8 + col4];  // 128 B/wave/step, coalesced
    o.x = fmaf(av, w.x, o.x);
    o.y = fmaf(av, w.y, o.y);
    o.z = fmaf(av, w.z, o.z);
    o.w = fmaf(av, w.w, o.w);
  }
  int tokj = tok0 + j;
  if (col4 < 4) ((float4*)(Bm + (size_t)tokj * NX))[col4] = o;
  else          ((float4*)(Cm + (size_t)tokj * NX))[col4 - 4] = o;
}

// ---------------- K2a: local chunk scans -> end states E only --------------
__global__ __launch_bounds__(256) void k2a_local(
    const float* __restrict__ hn, const float* __restrict__ delta,
    const float* __restrict__ Bm, const float* __restrict__ At,
    float* __restrict__ EX, float* __restrict__ T) {
  __shared__ float shn[CL][D];  // 32 KB
  __shared__ float sB[CL][NX];
  __shared__ float sdelta[CL];
  int ch = blockIdx.x & (NCH - 1);
  int b = blockIdx.x >> 6;
  int t = threadIdx.x;  // = d
  size_t tokbase = (size_t)(b * L + ch * CL);
  if (t < CL) sdelta[t] = delta[tokbase + t];
  for (int i = t; i < CL * NX; i += 256) ((float*)sB)[i] = Bm[tokbase * NX + i];
  {
    const float4* src = (const float4*)(hn + tokbase * D);
    float4* dst = (float4*)shn;
    #pragma unroll
    for (int i = 0; i < 8; ++i) dst[t + 256 * i] = src[t + 256 * i];
  }
  float a16[16];
  #pragma unroll
  for (int n = 0; n < 16; ++n) a16[n] = At[n * D + t];
  __syncthreads();
  if (t < 32) {
    float v = sdelta[t];
    #pragma unroll
    for (int off = 1; off < 32; off <<= 1) v += __shfl_xor(v, off);
    if (t == 0) T[b * NCH + ch] = v;
  }
  float x16[16];
  #pragma unroll
  for (int n = 0; n < 16; ++n) x16[n] = 0.f;
  for (int lo = 0; lo < CL; ++lo) {
    float dlt = sdelta[lo];
    float du = dlt * shn[lo][t];
    #pragma unroll
    for (int n = 0; n < 16; ++n)
      x16[n] = fmaf(exp2f(dlt * a16[n]), x16[n], du * sB[lo][n]);
  }
  size_t exbase = (size_t)blockIdx.x * (NX * D) + t;
  #pragma unroll
  for (int n = 0; n < 16; ++n) EX[exbase + n * D] = x16[n];
}

// ---------------- K2b: chunk-level scan, in-place E -> X, prefetch ---------
__global__ __launch_bounds__(256) void k2b_chunkscan(
    const float* __restrict__ At, const float* __restrict__ T,
    float* __restrict__ EX) {
  __shared__ float sT[NCH];
  int b = blockIdx.x >> 4;
  int rem = ((blockIdx.x & 15) << 8) | threadIdx.x;  // n*D + d
  if (threadIdx.x < NCH) sT[threadIdx.x] = T[b * NCH + threadIdx.x];
  __syncthreads();
  float A2 = At[rem];  // already *LOG2E
  size_t base = ((size_t)b << 18) + rem;
  float eq[4];
  #pragma unroll
  for (int j = 0; j < 4; ++j) eq[j] = EX[base + ((size_t)j << 12)];
  float x = 0.f;
  #pragma unroll 4
  for (int c = 0; c < NCH; ++c) {
    float e = eq[c & 3];
    if (c + 4 < NCH) eq[c & 3] = EX[base + ((size_t)(c + 4) << 12)];
    EX[base + ((size_t)c << 12)] = x;
    x = fmaf(exp2f(sT[c] * A2), x, e);
  }
}

// ---------------- K2c: re-scan with true init state + h recon + LN2 --------
__global__ __launch_bounds__(256) void k2c_scan2(
    const float* __restrict__ hn, const float* __restrict__ delta,
    const float* __restrict__ Bm, const float* __restrict__ Cm,
    const float* __restrict__ At, const float* __restrict__ EX,
    const float* __restrict__ muv, const float* __restrict__ irsv,
    const float* __restrict__ ng, const float* __restrict__ nb,
    const float* __restrict__ nfg, const float* __restrict__ nfb,
    float* __restrict__ hn2) {
  __shared__ float shn[CL][D];
  __shared__ float sB[CL][NX];
  __shared__ float sC[CL][NX];
  __shared__ float sdelta[CL];
  __shared__ float smu[CL];
  __shared__ float sirs[CL];
  int ch = blockIdx.x & (NCH - 1);
  int b = blockIdx.x >> 6;
  int t = threadIdx.x;  // = d
  size_t tokbase = (size_t)(b * L + ch * CL);
  if (t < CL) {
    sdelta[t] = delta[tokbase + t];
    smu[t] = muv[tokbase + t];
    sirs[t] = irsv[tokbase + t];
  }
  for (int i = t; i < CL * NX; i += 256) {
    ((float*)sB)[i] = Bm[tokbase * NX + i];
    ((float*)sC)[i] = Cm[tokbase * NX + i];
  }
  {
    const float4* src = (const float4*)(hn + tokbase * D);
    float4* dst = (float4*)shn;
    #pragma unroll
    for (int i = 0; i < 8; ++i) dst[t + 256 * i] = src[t + 256 * i];
  }
  float a16[16], x16[16];
  size_t exbase = (size_t)blockIdx.x * (NX * D) + t;
  #pragma unroll
  for (int n = 0; n < 16; ++n) {
    a16[n] = At[n * D + t];
    x16[n] = EX[exbase + n * D];
  }
  float nb_d = nb[t];
  float invg = 1.0f / ng[t];
  __syncthreads();
  for (int lo = 0; lo < CL; ++lo) {
    float dlt = sdelta[lo];
    float hv = shn[lo][t];
    float du = dlt * hv;
    float p = 0.f;
    #pragma unroll
    for (int n = 0; n < 16; ++n) {
      x16[n] = fmaf(exp2f(dlt * a16[n]), x16[n], du * sB[lo][n]);
      p = fmaf(x16[n], sC[lo][n], p);
    }
    float h = fmaf((hv - nb_d) * invg, sirs[lo], smu[lo]);
    shn[lo][t] = h + p;
  }
  __syncthreads();
  int w = t >> 6, lane = t & 63;
  float4 g4 = ((const float4*)nfg)[lane];
  float4 b4 = ((const float4*)nfb)[lane];
  for (int j = 0; j < 8; ++j) {
    int lo = w * 8 + j;
    float4 v = *(float4*)&shn[lo][lane * 4];
    float s1 = v.x + v.y + v.z + v.w;
    float s2 = v.x * v.x + v.y * v.y + v.z * v.z + v.w * v.w;
    #pragma unroll
    for (int off = 1; off < 64; off <<= 1) {
      s1 += __shfl_xor(s1, off);
      s2 += __shfl_xor(s2, off);
    }
    float mu2 = s1 * (1.f / D);
    float var2 = s2 * (1.f / D) - mu2 * mu2;
    float rstd2 = rsqrtf(var2 + 1e-5f);
    float4 o;
    o.x = (v.x - mu2) * rstd2 * g4.x + b4.x;
    o.y = (v.y - mu2) * rstd2 * g4.y + b4.y;
    o.z = (v.z - mu2) * rstd2 * g4.z + b4.z;
    o.w = (v.w - mu2) * rstd2 * g4.w + b4.w;
    ((float4*)(hn2 + (tokbase + lo) * D))[lane] = o;
  }
}

__device__ __forceinline__ float gelu_exact(float x) {
  return 0.5f * x * (1.f + erff(x * 0.70710678118654752440f));
}

// ---------------- K3b: MLP — LDS-staged W1 w/ register prefetch, f4 a-reads -
__global__ __launch_bounds__(256) void k3b_mlp(
    const float* __restrict__ hn2, const float* __restrict__ W1,
    const float* __restrict__ b1, const float* __restrict__ W2,
    const float* __restrict__ b2, float* __restrict__ out) {
  __shared__ float s_az[32 * 260];  // a at pitch 256 (phase 1), z at pitch 260
  __shared__ float s_w[32 * 256];   // one 32-row W1 k-tile (32 KB)
  int t = threadIdx.x;
  int tok0 = blockIdx.x * 32;
  {
    const float4* src = (const float4*)(hn2 + (size_t)tok0 * D);
    float4* dst = (float4*)s_az;  // a tile, pitch 256
    #pragma unroll
    for (int i = 0; i < 8; ++i) dst[t + 256 * i] = src[t + 256 * i];
  }
  const float4* W1g = (const float4*)W1;
  float4 r[8];  // prefetch registers: next W1 tile (8 float4/thread)
  #pragma unroll
  for (int i = 0; i < 8; ++i) r[i] = W1g[t + 256 * i];  // tile 0
  int dcol = t & 63, jrow = t >> 6;
  int d4 = dcol * 4, j8 = jrow * 8;
  float4 acc[8];
  #pragma unroll
  for (int jj = 0; jj < 8; ++jj) acc[jj] = make_float4(0.f, 0.f, 0.f, 0.f);
  float4* s_w4 = (float4*)s_w;
  const float4* A4 = (const float4*)s_az;   // [j][64 float4]
  for (int tile = 0; tile < 8; ++tile) {
    __syncthreads();  // prior tile's compute done (tile 0: a-stage done)
    #pragma unroll
    for (int i = 0; i < 8; ++i) s_w4[t + 256 * i] = r[i];
    __syncthreads();  // s_w ready
    if (tile < 7) {   // prefetch next tile; drains at next store, overlaps FMAs
      #pragma unroll
      for (int i = 0; i < 8; ++i) r[i] = W1g[(tile + 1) * 2048 + t + 256 * i];
    }
    #pragma unroll
    for (int k4 = 0; k4 < 8; ++k4) {
      float4 w0 = s_w4[(k4 * 4 + 0) * 64 + dcol];  // stride-1 b128, conflict-free
      float4 w1 = s_w4[(k4 * 4 + 1) * 64 + dcol];
      float4 w2 = s_w4[(k4 * 4 + 2) * 64 + dcol];
      float4 w3 = s_w4[(k4 * 4 + 3) * 64 + dcol];
      #pragma unroll
      for (int jj = 0; jj < 8; ++jj) {
        float4 a4 = A4[(j8 + jj) * 64 + tile * 8 + k4];  // wave-broadcast b128
        acc[jj].x = fmaf(a4.x, w0.x, acc[jj].x);
        acc[jj].y = fmaf(a4.x, w0.y, acc[jj].y);
        acc[jj].z = fmaf(a4.x, w0.z, acc[jj].z);
        acc[jj].w = fmaf(a4.x, w0.w, acc[jj].w);
        acc[jj].x = fmaf(a4.y, w1.x, acc[jj].x);
        acc[jj].y = fmaf(a4.y, w1.y, acc[jj].y);
        acc[jj].z = fmaf(a4.y, w1.z, acc[jj].z);
        acc[jj].w = fmaf(a4.y, w1.w, acc[jj].w);
        acc[jj].x = fmaf(a4.z, w2.x, acc[jj].x);
        acc[jj].y = fmaf(a4.z, w2.y, acc[jj].y);
        acc[jj].z = fmaf(a4.z, w2.z, acc[jj].z);
        acc[jj].w = fmaf(a4.z, w2.w, acc[jj].w);
        acc[jj].x = fmaf(a4.w, w3.x, acc[jj].x);
        acc[jj].y = fmaf(a4.w, w3.y, acc[jj].y);
        acc[jj].z = fmaf(a4.w, w3.z, acc[jj].z);
        acc[jj].w = fmaf(a4.w, w3.w, acc[jj].w);
      }
    }
  }
  float4 b1v = ((const float4*)b1)[dcol];
  __syncthreads();  // all a-reads done before z overwrites the buffer
  #pragma unroll
  for (int jj = 0; jj < 8; ++jj) {
    float4 v = acc[jj];
    v.x = gelu_exact(v.x + b1v.x);
    v.y = gelu_exact(v.y + b1v.y);
    v.z = gelu_exact(v.z + b1v.z);
    v.w = gelu_exact(v.w + b1v.w);
    *(float4*)&s_az[(j8 + jj) * 260 + d4] = v;  // z, pitch 260
  }
  __syncthreads();
  // phase 3: out[j][p] = z[j][:] . W2[:, p]; W2 global (32 KB, L2-hot)
  int j = t >> 3, p4 = t & 7;
  const float4* W2g = (const float4*)W2;  // [dd][8 float4]
  const float4* Z4 = (const float4*)s_az; // pitch 65 float4
  float4 o = make_float4(0.f, 0.f, 0.f, 0.f);
  #pragma unroll 4
  for (int dd4 = 0; dd4 < 64; ++dd4) {
    float4 z = Z4[j * 65 + dd4];  // bank-disjoint across the 8 j's per wave
    float4 wa = W2g[(dd4 * 4 + 0) * 8 + p4];
    float4 wb = W2g[(dd4 * 4 + 1) * 8 + p4];
    float4 wc = W2g[(dd4 * 4 + 2) * 8 + p4];
    float4 wd = W2g[(dd4 * 4 + 3) * 8 + p4];
    o.x = fmaf(z.x, wa.x, o.x); o.y = fmaf(z.x, wa.y, o.y);
    o.z = fmaf(z.x, wa.z, o.z); o.w = fmaf(z.x, wa.w, o.w);
    o.x = fmaf(z.y, wb.x, o.x); o.y = fmaf(z.y, wb.y, o.y);
    o.z = fmaf(z.y, wb.z, o.z); o.w = fmaf(z.y, wb.w, o.w);
    o.x = fmaf(z.z, wc.x, o.x); o.y = fmaf(z.z, wc.y, o.y);
    o.z = fmaf(z.z, wc.z, o.z); o.w = fmaf(z.z, wc.w, o.w);
    o.x = fmaf(z.w, wd.x, o.x); o.y = fmaf(z.w, wd.y, o.y);
    o.z = fmaf(z.w, wd.z, o.z); o.w = fmaf(z.w, wd.w, o.w);
  }
  float4 b2v = ((const float4*)b2)[p4];
  o.x += b2v.x; o.y += b2v.y; o.z += b2v.z; o.w += b2v.w;
  ((float4*)(out + (size_t)(tok0 + j) * 32))[p4] = o;
}

extern "C" void kernel_launch(void* const* d_in, const int* in_sizes, int n_in,
                              void* d_out, int out_size, void* d_ws, size_t ws_size,
                              hipStream_t stream) {
  const float* y    = (const float*)d_in[0];
  const float* Win  = (const float*)d_in[1];
  const float* bin_ = (const float*)d_in[2];
  const float* ng   = (const float*)d_in[3];
  const float* nb   = (const float*)d_in[4];
  const float* A    = (const float*)d_in[5];
  const float* WB   = (const float*)d_in[6];
  const float* WC   = (const float*)d_in[7];
  const float* qd   = (const float*)d_in[8];
  const float* pd   = (const float*)d_in[9];
  const float* nfg  = (const float*)d_in[10];
  const float* nfb  = (const float*)d_in[11];
  const float* W1   = (const float*)d_in[12];
  const float* b1   = (const float*)d_in[13];
  const float* W2   = (const float*)d_in[14];
  const float* b2   = (const float*)d_in[15];

  float* ws = (float*)d_ws;
  float* hnbuf = ws;                          // NTOK*D; hn -> (in-place) hn2
  float* delta = ws + 4194304;                // NTOK
  float* Bm    = delta + NTOK;                // NTOK*NX
  float* Cm    = Bm + NTOK * NX;              // NTOK*NX
  float* muv   = Cm + NTOK * NX;              // NTOK
  float* irsv  = muv + NTOK;                  // NTOK
  float* Tbuf  = irsv + NTOK;                 // NBATCH*NCH = 512
  float* At    = Tbuf + NBATCH * NCH;         // 4096
  float* Wbct  = At + D * NX;                 // 8192
  float* EX    = Wbct + D * 32;               // NBATCH*NCH*D*NX = 2M floats

  k0_at<<<16, 256, 0, stream>>>(A, At);
  k0b_wbct<<<32, 256, 0, stream>>>(WB, WC, Wbct);
  k1_front<<<NTOK / 32, 256, 0, stream>>>(y, Win, bin_, ng, nb, Wbct, qd, pd,
                                          hnbuf, delta, Bm, Cm, muv, irsv);
  k2a_local<<<NBATCH * NCH, 256, 0, stream>>>(hnbuf, delta, Bm, At, EX, Tbuf);
  k2b_chunkscan<<<NBATCH * 16, 256, 0, stream>>>(At, Tbuf, EX);
  k2c_scan2<<<NBATCH * NCH, 256, 0, stream>>>(hnbuf, delta, Bm, Cm, At, EX,
                                              muv, irsv, ng, nb, nfg, nfb,
                                              hnbuf);
  k3b_mlp<<<NTOK / 32, 256, 0, stream>>>(hnbuf, W1, b1, W2, b2, (float*)d_out);
}

// Round 9
// 264.423 us; speedup vs baseline: 1.0362x; 1.0362x over previous
//
#include <hip/hip_runtime.h>
#include <math.h>

#define D 256
#define NX 16
#define L 2048
#define NBATCH 8
#define NTOK (NBATCH * L)
#define CL 32
#define NCH (L / CL)  // 64
#define LOG2E 1.44269504088896340736f

// ---------------- K0: A -> At[n][d] with LOG2E folded ----------------
__global__ __launch_bounds__(256) void k0_at(const float* __restrict__ A,
                                             float* __restrict__ At) {
  int i = blockIdx.x * 256 + threadIdx.x;  // 4096 total
  int d = i >> 4, n = i & 15;
  At[n * D + d] = A[i] * LOG2E;
}

// ---------------- K0b: [WB;WC] -> Wbct[d][c] (c: 0-15 B, 16-31 C) ----------
__global__ __launch_bounds__(256) void k0b_wbct(const float* __restrict__ WB,
                                                const float* __restrict__ WC,
                                                float* __restrict__ Wbct) {
  int i = blockIdx.x * 256 + threadIdx.x;  // 8192 total
  int d = i >> 5, c = i & 31;
  Wbct[i] = (c < 16) ? WB[c * D + d] : WC[(c - 16) * D + d];
}

// ---------------- K1: 32-token block front end (weight-amortized GEMM) ------
__global__ __launch_bounds__(256) void k1_front(
    const float* __restrict__ y, const float* __restrict__ Win,
    const float* __restrict__ bin_, const float* __restrict__ ng,
    const float* __restrict__ nb, const float* __restrict__ Wbct,
    const float* __restrict__ qd, const float* __restrict__ pd,
    float* __restrict__ hn, float* __restrict__ delta,
    float* __restrict__ Bm, float* __restrict__ Cm,
    float* __restrict__ muv, float* __restrict__ irsv) {
  __shared__ float sy[32][32];    // y tile (reads are wave-uniform broadcasts)
  __shared__ float sh[32][260];   // hn tile, pitch 260 -> phase-C conflict-free
  int t = threadIdx.x;
  int tok0 = blockIdx.x * 32;
  {
    const float4* src = (const float4*)(y + (size_t)tok0 * 32);
    ((float4*)sy)[t] = src[t];  // 1024 floats, fully coalesced
  }
  __syncthreads();
  int dcol = t & 63;          // lane; owns d = dcol*4..+3
  int jrow = t >> 6;          // wave id; wave owns tokens jrow*8..+7
  int d4 = dcol * 4;
  float4 bv = ((const float4*)bin_)[dcol];
  float4 acc[8];
  #pragma unroll
  for (int jj = 0; jj < 8; ++jj) acc[jj] = bv;
  const float4* Win4 = (const float4*)Win;  // [k][64 float4]
  #pragma unroll
  for (int k = 0; k < 32; ++k) {
    float4 wv = Win4[k * 64 + dcol];
    #pragma unroll
    for (int jj = 0; jj < 8; ++jj) {
      float av = sy[jrow * 8 + jj][k];  // wave-uniform broadcast
      acc[jj].x = fmaf(av, wv.x, acc[jj].x);
      acc[jj].y = fmaf(av, wv.y, acc[jj].y);
      acc[jj].z = fmaf(av, wv.z, acc[jj].z);
      acc[jj].w = fmaf(av, wv.w, acc[jj].w);
    }
  }
  // LN + delta per token, straight from registers
  float4 g4 = ((const float4*)ng)[dcol];
  float4 nb4 = ((const float4*)nb)[dcol];
  float4 q4 = ((const float4*)qd)[dcol];
  float pd0 = pd[0];
  #pragma unroll
  for (int jj = 0; jj < 8; ++jj) {
    int j = jrow * 8 + jj;
    int tok = tok0 + j;
    float4 a = acc[jj];
    float s1 = a.x + a.y + a.z + a.w;
    float s2 = a.x * a.x + a.y * a.y + a.z * a.z + a.w * a.w;
    #pragma unroll
    for (int off = 1; off < 64; off <<= 1) {
      s1 += __shfl_xor(s1, off);
      s2 += __shfl_xor(s2, off);
    }
    float mu = s1 * (1.f / D);
    float var = s2 * (1.f / D) - mu * mu;
    float rstd = rsqrtf(var + 1e-5f);
    if (dcol == 0) { muv[tok] = mu; irsv[tok] = sqrtf(var + 1e-5f); }
    float4 v4;
    v4.x = (a.x - mu) * rstd * g4.x + nb4.x;
    v4.y = (a.y - mu) * rstd * g4.y + nb4.y;
    v4.z = (a.z - mu) * rstd * g4.z + nb4.z;
    v4.w = (a.w - mu) * rstd * g4.w + nb4.w;
    ((float4*)(hn + (size_t)tok * D))[dcol] = v4;
    *(float4*)&sh[j][d4] = v4;
    float dd = v4.x * q4.x + v4.y * q4.y + v4.z * q4.z + v4.w * q4.w;
    #pragma unroll
    for (int off = 1; off < 64; off <<= 1) dd += __shfl_xor(dd, off);
    if (dcol == 0) {
      float xx = pd0 + dd;
      delta[tok] = (xx > 20.f) ? xx : log1pf(expf(xx));
    }
  }
  __syncthreads();
  // Phase C: [Bm|Cm](32 tok x 32 cols) = sh(32x256) @ Wbct(256x32)
  int col4 = t & 7;   // float4 column group (cols col4*4..+3)
  int j = t >> 3;     // token 0..31
  const float4* W4 = (const float4*)Wbct;  // [d][8 float4]
  float4 o = make_float4(0.f, 0.f, 0.f, 0.f);
  #pragma unroll 8
  for (int d = 0; d < 256; ++d) {
    float av = sh[j][d];          // 8 j's/wave, banks 4j%32 offset -> no conflict
    float4 w = W4[d * 8 + col4];  // 128 B/wave/step, coalesced
    o.x = fmaf(av, w.x, o.x);
    o.y = fmaf(av, w.y, o.y);
    o.z = fmaf(av, w.z, o.z);
    o.w = fmaf(av, w.w, o.w);
  }
  int tokj = tok0 + j;
  if (col4 < 4) ((float4*)(Bm + (size_t)tokj * NX))[col4] = o;
  else          ((float4*)(Cm + (size_t)tokj * NX))[col4 - 4] = o;
}

// ---------------- K2a: local chunk scans -> end states E only --------------
__global__ __launch_bounds__(256) void k2a_local(
    const float* __restrict__ hn, const float* __restrict__ delta,
    const float* __restrict__ Bm, const float* __restrict__ At,
    float* __restrict__ EX, float* __restrict__ T) {
  __shared__ float shn[CL][D];  // 32 KB
  __shared__ float sB[CL][NX];
  __shared__ float sdelta[CL];
  int ch = blockIdx.x & (NCH - 1);
  int b = blockIdx.x >> 6;
  int t = threadIdx.x;  // = d
  size_t tokbase = (size_t)(b * L + ch * CL);
  if (t < CL) sdelta[t] = delta[tokbase + t];
  for (int i = t; i < CL * NX; i += 256) ((float*)sB)[i] = Bm[tokbase * NX + i];
  {
    const float4* src = (const float4*)(hn + tokbase * D);
    float4* dst = (float4*)shn;
    #pragma unroll
    for (int i = 0; i < 8; ++i) dst[t + 256 * i] = src[t + 256 * i];
  }
  float a16[16];
  #pragma unroll
  for (int n = 0; n < 16; ++n) a16[n] = At[n * D + t];
  __syncthreads();
  if (t < 32) {
    float v = sdelta[t];
    #pragma unroll
    for (int off = 1; off < 32; off <<= 1) v += __shfl_xor(v, off);
    if (t == 0) T[b * NCH + ch] = v;
  }
  float x16[16];
  #pragma unroll
  for (int n = 0; n < 16; ++n) x16[n] = 0.f;
  for (int lo = 0; lo < CL; ++lo) {
    float dlt = sdelta[lo];
    float du = dlt * shn[lo][t];
    #pragma unroll
    for (int n = 0; n < 16; ++n)
      x16[n] = fmaf(exp2f(dlt * a16[n]), x16[n], du * sB[lo][n]);
  }
  size_t exbase = (size_t)blockIdx.x * (NX * D) + t;
  #pragma unroll
  for (int n = 0; n < 16; ++n) EX[exbase + n * D] = x16[n];
}

// ---------------- K2b: chunk-level scan, in-place E -> X, prefetch ---------
__global__ __launch_bounds__(256) void k2b_chunkscan(
    const float* __restrict__ At, const float* __restrict__ T,
    float* __restrict__ EX) {
  __shared__ float sT[NCH];
  int b = blockIdx.x >> 4;
  int rem = ((blockIdx.x & 15) << 8) | threadIdx.x;  // n*D + d
  if (threadIdx.x < NCH) sT[threadIdx.x] = T[b * NCH + threadIdx.x];
  __syncthreads();
  float A2 = At[rem];  // already *LOG2E
  size_t base = ((size_t)b << 18) + rem;
  float eq[4];
  #pragma unroll
  for (int j = 0; j < 4; ++j) eq[j] = EX[base + ((size_t)j << 12)];
  float x = 0.f;
  #pragma unroll 4
  for (int c = 0; c < NCH; ++c) {
    float e = eq[c & 3];
    if (c + 4 < NCH) eq[c & 3] = EX[base + ((size_t)(c + 4) << 12)];
    EX[base + ((size_t)c << 12)] = x;
    x = fmaf(exp2f(sT[c] * A2), x, e);
  }
}

// ---------------- K2c: re-scan with true init state + h recon + LN2 --------
__global__ __launch_bounds__(256) void k2c_scan2(
    const float* __restrict__ hn, const float* __restrict__ delta,
    const float* __restrict__ Bm, const float* __restrict__ Cm,
    const float* __restrict__ At, const float* __restrict__ EX,
    const float* __restrict__ muv, const float* __restrict__ irsv,
    const float* __restrict__ ng, const float* __restrict__ nb,
    const float* __restrict__ nfg, const float* __restrict__ nfb,
    float* __restrict__ hn2) {
  __shared__ float shn[CL][D];
  __shared__ float sB[CL][NX];
  __shared__ float sC[CL][NX];
  __shared__ float sdelta[CL];
  __shared__ float smu[CL];
  __shared__ float sirs[CL];
  int ch = blockIdx.x & (NCH - 1);
  int b = blockIdx.x >> 6;
  int t = threadIdx.x;  // = d
  size_t tokbase = (size_t)(b * L + ch * CL);
  if (t < CL) {
    sdelta[t] = delta[tokbase + t];
    smu[t] = muv[tokbase + t];
    sirs[t] = irsv[tokbase + t];
  }
  for (int i = t; i < CL * NX; i += 256) {
    ((float*)sB)[i] = Bm[tokbase * NX + i];
    ((float*)sC)[i] = Cm[tokbase * NX + i];
  }
  {
    const float4* src = (const float4*)(hn + tokbase * D);
    float4* dst = (float4*)shn;
    #pragma unroll
    for (int i = 0; i < 8; ++i) dst[t + 256 * i] = src[t + 256 * i];
  }
  float a16[16], x16[16];
  size_t exbase = (size_t)blockIdx.x * (NX * D) + t;
  #pragma unroll
  for (int n = 0; n < 16; ++n) {
    a16[n] = At[n * D + t];
    x16[n] = EX[exbase + n * D];
  }
  float nb_d = nb[t];
  float invg = 1.0f / ng[t];
  __syncthreads();
  for (int lo = 0; lo < CL; ++lo) {
    float dlt = sdelta[lo];
    float hv = shn[lo][t];
    float du = dlt * hv;
    float p = 0.f;
    #pragma unroll
    for (int n = 0; n < 16; ++n) {
      x16[n] = fmaf(exp2f(dlt * a16[n]), x16[n], du * sB[lo][n]);
      p = fmaf(x16[n], sC[lo][n], p);
    }
    float h = fmaf((hv - nb_d) * invg, sirs[lo], smu[lo]);
    shn[lo][t] = h + p;
  }
  __syncthreads();
  int w = t >> 6, lane = t & 63;
  float4 g4 = ((const float4*)nfg)[lane];
  float4 b4 = ((const float4*)nfb)[lane];
  for (int j = 0; j < 8; ++j) {
    int lo = w * 8 + j;
    float4 v = *(float4*)&shn[lo][lane * 4];
    float s1 = v.x + v.y + v.z + v.w;
    float s2 = v.x * v.x + v.y * v.y + v.z * v.z + v.w * v.w;
    #pragma unroll
    for (int off = 1; off < 64; off <<= 1) {
      s1 += __shfl_xor(s1, off);
      s2 += __shfl_xor(s2, off);
    }
    float mu2 = s1 * (1.f / D);
    float var2 = s2 * (1.f / D) - mu2 * mu2;
    float rstd2 = rsqrtf(var2 + 1e-5f);
    float4 o;
    o.x = (v.x - mu2) * rstd2 * g4.x + b4.x;
    o.y = (v.y - mu2) * rstd2 * g4.y + b4.y;
    o.z = (v.z - mu2) * rstd2 * g4.z + b4.z;
    o.w = (v.w - mu2) * rstd2 * g4.w + b4.w;
    ((float4*)(hn2 + (tokbase + lo) * D))[lane] = o;
  }
}

__device__ __forceinline__ float gelu_exact(float x) {
  return 0.5f * x * (1.f + erff(x * 0.70710678118654752440f));
}

// ---------------- K3b: MLP — r6 structure + b128 a/z reads (no reg prefetch)
__global__ __launch_bounds__(256) void k3b_mlp(
    const float* __restrict__ hn2, const float* __restrict__ W1,
    const float* __restrict__ b1, const float* __restrict__ W2,
    const float* __restrict__ b2, float* __restrict__ out) {
  __shared__ float s_az[32 * 260];  // a at pitch 256 (phase 1), z at pitch 260
  __shared__ float s_w[32 * 256];   // W1 k-tile, then W2
  int t = threadIdx.x;
  int tok0 = blockIdx.x * 32;
  {
    const float4* src = (const float4*)(hn2 + (size_t)tok0 * D);
    float4* dst = (float4*)s_az;  // a tile, pitch 256
    #pragma unroll
    for (int i = 0; i < 8; ++i) dst[t + 256 * i] = src[t + 256 * i];
  }
  int dcol = t & 63, jrow = t >> 6;
  int d4 = dcol * 4, j8 = jrow * 8;
  float4 acc[8];
  #pragma unroll
  for (int jj = 0; jj < 8; ++jj) acc[jj] = make_float4(0.f, 0.f, 0.f, 0.f);
  const float4* W1g = (const float4*)W1;
  float4* s_w4 = (float4*)s_w;
  const float4* A4 = (const float4*)s_az;   // [j][64 float4]
  for (int tile = 0; tile < 8; ++tile) {
    __syncthreads();  // prior tile's reads done (tile 0: a-stage done)
    #pragma unroll
    for (int i = 0; i < 8; ++i)
      s_w4[t + 256 * i] = W1g[tile * 2048 + t + 256 * i];
    __syncthreads();  // s_w ready
    #pragma unroll
    for (int k4 = 0; k4 < 8; ++k4) {
      float4 w0 = s_w4[(k4 * 4 + 0) * 64 + dcol];  // stride-1 b128, no conflict
      float4 w1 = s_w4[(k4 * 4 + 1) * 64 + dcol];
      float4 w2 = s_w4[(k4 * 4 + 2) * 64 + dcol];
      float4 w3 = s_w4[(k4 * 4 + 3) * 64 + dcol];
      #pragma unroll
      for (int jj = 0; jj < 8; ++jj) {
        float4 a4 = A4[(j8 + jj) * 64 + tile * 8 + k4];  // wave-broadcast b128
        acc[jj].x = fmaf(a4.x, w0.x, acc[jj].x);
        acc[jj].y = fmaf(a4.x, w0.y, acc[jj].y);
        acc[jj].z = fmaf(a4.x, w0.z, acc[jj].z);
        acc[jj].w = fmaf(a4.x, w0.w, acc[jj].w);
        acc[jj].x = fmaf(a4.y, w1.x, acc[jj].x);
        acc[jj].y = fmaf(a4.y, w1.y, acc[jj].y);
        acc[jj].z = fmaf(a4.y, w1.z, acc[jj].z);
        acc[jj].w = fmaf(a4.y, w1.w, acc[jj].w);
        acc[jj].x = fmaf(a4.z, w2.x, acc[jj].x);
        acc[jj].y = fmaf(a4.z, w2.y, acc[jj].y);
        acc[jj].z = fmaf(a4.z, w2.z, acc[jj].z);
        acc[jj].w = fmaf(a4.z, w2.w, acc[jj].w);
        acc[jj].x = fmaf(a4.w, w3.x, acc[jj].x);
        acc[jj].y = fmaf(a4.w, w3.y, acc[jj].y);
        acc[jj].z = fmaf(a4.w, w3.z, acc[jj].z);
        acc[jj].w = fmaf(a4.w, w3.w, acc[jj].w);
      }
    }
  }
  float4 b1v = ((const float4*)b1)[dcol];
  __syncthreads();  // all a-reads (s_az) + w-reads (s_w) done
  #pragma unroll
  for (int jj = 0; jj < 8; ++jj) {
    float4 v = acc[jj];
    v.x = gelu_exact(v.x + b1v.x);
    v.y = gelu_exact(v.y + b1v.y);
    v.z = gelu_exact(v.z + b1v.z);
    v.w = gelu_exact(v.w + b1v.w);
    *(float4*)&s_az[(j8 + jj) * 260 + d4] = v;  // z, pitch 260
  }
  {
    const float4* w2s = (const float4*)W2;  // stage W2 into s_w
    #pragma unroll
    for (int i = 0; i < 8; ++i) s_w4[t + 256 * i] = w2s[t + 256 * i];
  }
  __syncthreads();
  // phase 3: out[j][p] = z[j][:] . W2[:, p]
  int j = t >> 3, p4 = t & 7;
  const float4* Z4 = (const float4*)s_az;  // pitch 65 float4
  float4 o = make_float4(0.f, 0.f, 0.f, 0.f);
  #pragma unroll 4
  for (int dd4 = 0; dd4 < 64; ++dd4) {
    float4 z = Z4[j * 65 + dd4];            // banks 4(j+dd4)%32 -> no conflict
    float4 wa = s_w4[(dd4 * 4 + 0) * 8 + p4];  // banks 4*p4 quads -> disjoint
    float4 wb = s_w4[(dd4 * 4 + 1) * 8 + p4];
    float4 wc = s_w4[(dd4 * 4 + 2) * 8 + p4];
    float4 wd = s_w4[(dd4 * 4 + 3) * 8 + p4];
    o.x = fmaf(z.x, wa.x, o.x); o.y = fmaf(z.x, wa.y, o.y);
    o.z = fmaf(z.x, wa.z, o.z); o.w = fmaf(z.x, wa.w, o.w);
    o.x = fmaf(z.y, wb.x, o.x); o.y = fmaf(z.y, wb.y, o.y);
    o.z = fmaf(z.y, wb.z, o.z); o.w = fmaf(z.y, wb.w, o.w);
    o.x = fmaf(z.z, wc.x, o.x); o.y = fmaf(z.z, wc.y, o.y);
    o.z = fmaf(z.z, wc.z, o.z); o.w = fmaf(z.z, wc.w, o.w);
    o.x = fmaf(z.w, wd.x, o.x); o.y = fmaf(z.w, wd.y, o.y);
    o.z = fmaf(z.w, wd.z, o.z); o.w = fmaf(z.w, wd.w, o.w);
  }
  float4 b2v = ((const float4*)b2)[p4];
  o.x += b2v.x; o.y += b2v.y; o.z += b2v.z; o.w += b2v.w;
  ((float4*)(out + (size_t)(tok0 + j) * 32))[p4] = o;
}

extern "C" void kernel_launch(void* const* d_in, const int* in_sizes, int n_in,
                              void* d_out, int out_size, void* d_ws, size_t ws_size,
                              hipStream_t stream) {
  const float* y    = (const float*)d_in[0];
  const float* Win  = (const float*)d_in[1];
  const float* bin_ = (const float*)d_in[2];
  const float* ng   = (const float*)d_in[3];
  const float* nb   = (const float*)d_in[4];
  const float* A    = (const float*)d_in[5];
  const float* WB   = (const float*)d_in[6];
  const float* WC   = (const float*)d_in[7];
  const float* qd   = (const float*)d_in[8];
  const float* pd   = (const float*)d_in[9];
  const float* nfg  = (const float*)d_in[10];
  const float* nfb  = (const float*)d_in[11];
  const float* W1   = (const float*)d_in[12];
  const float* b1   = (const float*)d_in[13];
  const float* W2   = (const float*)d_in[14];
  const float* b2   = (const float*)d_in[15];

  float* ws = (float*)d_ws;
  float* hnbuf = ws;                          // NTOK*D; hn -> (in-place) hn2
  float* delta = ws + 4194304;                // NTOK
  float* Bm    = delta + NTOK;                // NTOK*NX
  float* Cm    = Bm + NTOK * NX;              // NTOK*NX
  float* muv   = Cm + NTOK * NX;              // NTOK
  float* irsv  = muv + NTOK;                  // NTOK
  float* Tbuf  = irsv + NTOK;                 // NBATCH*NCH = 512
  float* At    = Tbuf + NBATCH * NCH;         // 4096
  float* Wbct  = At + D * NX;                 // 8192
  float* EX    = Wbct + D * 32;               // NBATCH*NCH*D*NX = 2M floats

  k0_at<<<16, 256, 0, stream>>>(A, At);
  k0b_wbct<<<32, 256, 0, stream>>>(WB, WC, Wbct);
  k1_front<<<NTOK / 32, 256, 0, stream>>>(y, Win, bin_, ng, nb, Wbct, qd, pd,
                                          hnbuf, delta, Bm, Cm, muv, irsv);
  k2a_local<<<NBATCH * NCH, 256, 0, stream>>>(hnbuf, delta, Bm, At, EX, Tbuf);
  k2b_chunkscan<<<NBATCH * 16, 256, 0, stream>>>(At, Tbuf, EX);
  k2c_scan2<<<NBATCH * NCH, 256, 0, stream>>>(hnbuf, delta, Bm, Cm, At, EX,
                                              muv, irsv, ng, nb, nfg, nfb,
                                              hnbuf);
  k3b_mlp<<<NTOK / 32, 256, 0, stream>>>(hnbuf, W1, b1, W2, b2, (float*)d_out);
}

// Round 10
// 250.898 us; speedup vs baseline: 1.0921x; 1.0539x over previous
//
#include <hip/hip_runtime.h>
#include <math.h>

#define D 256
#define NX 16
#define L 2048
#define NBATCH 8
#define NTOK (NBATCH * L)
#define CL 32
#define NCH (L / CL)  // 64
#define LOG2E 1.44269504088896340736f

// ---------------- K0: At[n][d] = A[d][n]*LOG2E ; Wbct[d][c] = [WB;WC]^T -----
__global__ __launch_bounds__(256) void k0_prep(const float* __restrict__ A,
                                               const float* __restrict__ WB,
                                               const float* __restrict__ WC,
                                               float* __restrict__ At,
                                               float* __restrict__ Wbct) {
  int i = blockIdx.x * 256 + threadIdx.x;  // 12288 total
  if (i < 4096) {
    int d = i >> 4, n = i & 15;
    At[n * D + d] = A[i] * LOG2E;
  } else {
    int j = i - 4096;  // 8192
    int d = j >> 5, c = j & 31;
    Wbct[j] = (c < 16) ? WB[c * D + d] : WC[(c - 16) * D + d];
  }
}

// ---------------- K1: 32-token block front end (weight-amortized GEMM) ------
__global__ __launch_bounds__(256) void k1_front(
    const float* __restrict__ y, const float* __restrict__ Win,
    const float* __restrict__ bin_, const float* __restrict__ ng,
    const float* __restrict__ nb, const float* __restrict__ Wbct,
    const float* __restrict__ qd, const float* __restrict__ pd,
    float* __restrict__ hn, float* __restrict__ delta,
    float* __restrict__ Bm, float* __restrict__ Cm,
    float* __restrict__ muv, float* __restrict__ irsv) {
  __shared__ float sy[32][32];    // y tile (reads are wave-uniform broadcasts)
  __shared__ float sh[32][260];   // hn tile, pitch 260 -> phase-C conflict-free
  int t = threadIdx.x;
  int tok0 = blockIdx.x * 32;
  {
    const float4* src = (const float4*)(y + (size_t)tok0 * 32);
    ((float4*)sy)[t] = src[t];  // 1024 floats, fully coalesced
  }
  __syncthreads();
  int dcol = t & 63;          // lane; owns d = dcol*4..+3
  int jrow = t >> 6;          // wave id; wave owns tokens jrow*8..+7
  int d4 = dcol * 4;
  float4 bv = ((const float4*)bin_)[dcol];
  float4 acc[8];
  #pragma unroll
  for (int jj = 0; jj < 8; ++jj) acc[jj] = bv;
  const float4* Win4 = (const float4*)Win;  // [k][64 float4]
  #pragma unroll
  for (int k = 0; k < 32; ++k) {
    float4 wv = Win4[k * 64 + dcol];
    #pragma unroll
    for (int jj = 0; jj < 8; ++jj) {
      float av = sy[jrow * 8 + jj][k];  // wave-uniform broadcast
      acc[jj].x = fmaf(av, wv.x, acc[jj].x);
      acc[jj].y = fmaf(av, wv.y, acc[jj].y);
      acc[jj].z = fmaf(av, wv.z, acc[jj].z);
      acc[jj].w = fmaf(av, wv.w, acc[jj].w);
    }
  }
  // LN + delta per token, straight from registers
  float4 g4 = ((const float4*)ng)[dcol];
  float4 nb4 = ((const float4*)nb)[dcol];
  float4 q4 = ((const float4*)qd)[dcol];
  float pd0 = pd[0];
  #pragma unroll
  for (int jj = 0; jj < 8; ++jj) {
    int j = jrow * 8 + jj;
    int tok = tok0 + j;
    float4 a = acc[jj];
    float s1 = a.x + a.y + a.z + a.w;
    float s2 = a.x * a.x + a.y * a.y + a.z * a.z + a.w * a.w;
    #pragma unroll
    for (int off = 1; off < 64; off <<= 1) {
      s1 += __shfl_xor(s1, off);
      s2 += __shfl_xor(s2, off);
    }
    float mu = s1 * (1.f / D);
    float var = s2 * (1.f / D) - mu * mu;
    float rstd = rsqrtf(var + 1e-5f);
    if (dcol == 0) { muv[tok] = mu; irsv[tok] = sqrtf(var + 1e-5f); }
    float4 v4;
    v4.x = (a.x - mu) * rstd * g4.x + nb4.x;
    v4.y = (a.y - mu) * rstd * g4.y + nb4.y;
    v4.z = (a.z - mu) * rstd * g4.z + nb4.z;
    v4.w = (a.w - mu) * rstd * g4.w + nb4.w;
    ((float4*)(hn + (size_t)tok * D))[dcol] = v4;
    *(float4*)&sh[j][d4] = v4;
    float dd = v4.x * q4.x + v4.y * q4.y + v4.z * q4.z + v4.w * q4.w;
    #pragma unroll
    for (int off = 1; off < 64; off <<= 1) dd += __shfl_xor(dd, off);
    if (dcol == 0) {
      float xx = pd0 + dd;
      delta[tok] = (xx > 20.f) ? xx : log1pf(expf(xx));
    }
  }
  __syncthreads();
  // Phase C: [Bm|Cm](32 tok x 32 cols) = sh(32x256) @ Wbct(256x32)
  int col4 = t & 7;   // float4 column group (cols col4*4..+3)
  int j = t >> 3;     // token 0..31
  const float4* W4 = (const float4*)Wbct;  // [d][8 float4]
  float4 o = make_float4(0.f, 0.f, 0.f, 0.f);
  #pragma unroll 8
  for (int d = 0; d < 256; ++d) {
    float av = sh[j][d];          // 8 j's/wave, banks 4j%32 offset -> no conflict
    float4 w = W4[d * 8 + col4];  // 128 B/wave/step, coalesced
    o.x = fmaf(av, w.x, o.x);
    o.y = fmaf(av, w.y, o.y);
    o.z = fmaf(av, w.z, o.z);
    o.w = fmaf(av, w.w, o.w);
  }
  int tokj = tok0 + j;
  if (col4 < 4) ((float4*)(Bm + (size_t)tokj * NX))[col4] = o;
  else          ((float4*)(Cm + (size_t)tokj * NX))[col4 - 4] = o;
}

// ---------------- K2a: local chunk scans -> end states E only --------------
__global__ __launch_bounds__(256) void k2a_local(
    const float* __restrict__ hn, const float* __restrict__ delta,
    const float* __restrict__ Bm, const float* __restrict__ At,
    float* __restrict__ EX, float* __restrict__ T) {
  __shared__ float shn[CL][D];  // 32 KB
  __shared__ float sB[CL][NX];
  __shared__ float sdelta[CL];
  int ch = blockIdx.x & (NCH - 1);
  int b = blockIdx.x >> 6;
  int t = threadIdx.x;  // = d
  size_t tokbase = (size_t)(b * L + ch * CL);
  if (t < CL) sdelta[t] = delta[tokbase + t];
  for (int i = t; i < CL * NX; i += 256) ((float*)sB)[i] = Bm[tokbase * NX + i];
  {
    const float4* src = (const float4*)(hn + tokbase * D);
    float4* dst = (float4*)shn;
    #pragma unroll
    for (int i = 0; i < 8; ++i) dst[t + 256 * i] = src[t + 256 * i];
  }
  float a16[16];
  #pragma unroll
  for (int n = 0; n < 16; ++n) a16[n] = At[n * D + t];
  __syncthreads();
  if (t < 32) {
    float v = sdelta[t];
    #pragma unroll
    for (int off = 1; off < 32; off <<= 1) v += __shfl_xor(v, off);
    if (t == 0) T[b * NCH + ch] = v;
  }
  float x16[16];
  #pragma unroll
  for (int n = 0; n < 16; ++n) x16[n] = 0.f;
  for (int lo = 0; lo < CL; ++lo) {
    float dlt = sdelta[lo];
    float du = dlt * shn[lo][t];
    #pragma unroll
    for (int n = 0; n < 16; ++n)
      x16[n] = fmaf(exp2f(dlt * a16[n]), x16[n], du * sB[lo][n]);
  }
  size_t exbase = (size_t)blockIdx.x * (NX * D) + t;
  #pragma unroll
  for (int n = 0; n < 16; ++n) EX[exbase + n * D] = x16[n];
}

// ---------------- K2b: chunk-level scan, in-place E -> X, prefetch ---------
__global__ __launch_bounds__(256) void k2b_chunkscan(
    const float* __restrict__ At, const float* __restrict__ T,
    float* __restrict__ EX) {
  __shared__ float sT[NCH];
  int b = blockIdx.x >> 4;
  int rem = ((blockIdx.x & 15) << 8) | threadIdx.x;  // n*D + d
  if (threadIdx.x < NCH) sT[threadIdx.x] = T[b * NCH + threadIdx.x];
  __syncthreads();
  float A2 = At[rem];  // already *LOG2E
  size_t base = ((size_t)b << 18) + rem;
  float eq[4];
  #pragma unroll
  for (int j = 0; j < 4; ++j) eq[j] = EX[base + ((size_t)j << 12)];
  float x = 0.f;
  #pragma unroll 4
  for (int c = 0; c < NCH; ++c) {
    float e = eq[c & 3];
    if (c + 4 < NCH) eq[c & 3] = EX[base + ((size_t)(c + 4) << 12)];
    EX[base + ((size_t)c << 12)] = x;
    x = fmaf(exp2f(sT[c] * A2), x, e);
  }
}

// ---------------- K2c: re-scan with true init state + h recon + LN2 --------
__global__ __launch_bounds__(256) void k2c_scan2(
    const float* __restrict__ hn, const float* __restrict__ delta,
    const float* __restrict__ Bm, const float* __restrict__ Cm,
    const float* __restrict__ At, const float* __restrict__ EX,
    const float* __restrict__ muv, const float* __restrict__ irsv,
    const float* __restrict__ ng, const float* __restrict__ nb,
    const float* __restrict__ nfg, const float* __restrict__ nfb,
    float* __restrict__ hn2) {
  __shared__ float shn[CL][D];
  __shared__ float sB[CL][NX];
  __shared__ float sC[CL][NX];
  __shared__ float sdelta[CL];
  __shared__ float smu[CL];
  __shared__ float sirs[CL];
  int ch = blockIdx.x & (NCH - 1);
  int b = blockIdx.x >> 6;
  int t = threadIdx.x;  // = d
  size_t tokbase = (size_t)(b * L + ch * CL);
  if (t < CL) {
    sdelta[t] = delta[tokbase + t];
    smu[t] = muv[tokbase + t];
    sirs[t] = irsv[tokbase + t];
  }
  for (int i = t; i < CL * NX; i += 256) {
    ((float*)sB)[i] = Bm[tokbase * NX + i];
    ((float*)sC)[i] = Cm[tokbase * NX + i];
  }
  {
    const float4* src = (const float4*)(hn + tokbase * D);
    float4* dst = (float4*)shn;
    #pragma unroll
    for (int i = 0; i < 8; ++i) dst[t + 256 * i] = src[t + 256 * i];
  }
  float a16[16], x16[16];
  size_t exbase = (size_t)blockIdx.x * (NX * D) + t;
  #pragma unroll
  for (int n = 0; n < 16; ++n) {
    a16[n] = At[n * D + t];
    x16[n] = EX[exbase + n * D];
  }
  float nb_d = nb[t];
  float invg = 1.0f / ng[t];
  __syncthreads();
  for (int lo = 0; lo < CL; ++lo) {
    float dlt = sdelta[lo];
    float hv = shn[lo][t];
    float du = dlt * hv;
    float p = 0.f;
    #pragma unroll
    for (int n = 0; n < 16; ++n) {
      x16[n] = fmaf(exp2f(dlt * a16[n]), x16[n], du * sB[lo][n]);
      p = fmaf(x16[n], sC[lo][n], p);
    }
    float h = fmaf((hv - nb_d) * invg, sirs[lo], smu[lo]);
    shn[lo][t] = h + p;
  }
  __syncthreads();
  int w = t >> 6, lane = t & 63;
  float4 g4 = ((const float4*)nfg)[lane];
  float4 b4 = ((const float4*)nfb)[lane];
  for (int j = 0; j < 8; ++j) {
    int lo = w * 8 + j;
    float4 v = *(float4*)&shn[lo][lane * 4];
    float s1 = v.x + v.y + v.z + v.w;
    float s2 = v.x * v.x + v.y * v.y + v.z * v.z + v.w * v.w;
    #pragma unroll
    for (int off = 1; off < 64; off <<= 1) {
      s1 += __shfl_xor(s1, off);
      s2 += __shfl_xor(s2, off);
    }
    float mu2 = s1 * (1.f / D);
    float var2 = s2 * (1.f / D) - mu2 * mu2;
    float rstd2 = rsqrtf(var2 + 1e-5f);
    float4 o;
    o.x = (v.x - mu2) * rstd2 * g4.x + b4.x;
    o.y = (v.y - mu2) * rstd2 * g4.y + b4.y;
    o.z = (v.z - mu2) * rstd2 * g4.z + b4.z;
    o.w = (v.w - mu2) * rstd2 * g4.w + b4.w;
    ((float4*)(hn2 + (tokbase + lo) * D))[lane] = o;
  }
}

__device__ __forceinline__ float gelu_exact(float x) {
  return 0.5f * x * (1.f + erff(x * 0.70710678118654752440f));
}

// ---------------- K3b: MLP — exact r6 version (local optimum; do not touch) -
__global__ __launch_bounds__(256) void k3b_mlp(
    const float* __restrict__ hn2, const float* __restrict__ W1,
    const float* __restrict__ b1, const float* __restrict__ W2,
    const float* __restrict__ b2, float* __restrict__ out) {
  __shared__ float s_az[32 * 260];
  __shared__ float s_w[32 * 256];
  int t = threadIdx.x;
  int tok0 = blockIdx.x * 32;
  {
    const float4* src = (const float4*)(hn2 + (size_t)tok0 * D);
    float4* dst = (float4*)s_az;
    for (int i = t; i < 2048; i += 256) dst[i] = src[i];
  }
  float4 acc[8];
  #pragma unroll
  for (int jj = 0; jj < 8; ++jj) acc[jj] = make_float4(0.f, 0.f, 0.f, 0.f);
  int dcol = t & 63, jrow = t >> 6;
  int d4 = dcol * 4, j8 = jrow * 8;
  for (int kb = 0; kb < 256; kb += 32) {
    __syncthreads();
    {
      const float4* wsrc = (const float4*)(W1 + kb * D);
      float4* wdst = (float4*)s_w;
      for (int i = t; i < 2048; i += 256) wdst[i] = wsrc[i];
    }
    __syncthreads();
    #pragma unroll 8
    for (int k = 0; k < 32; ++k) {
      float4 w = *(float4*)&s_w[k * D + d4];
      #pragma unroll
      for (int jj = 0; jj < 8; ++jj) {
        float av = s_az[(j8 + jj) * 256 + kb + k];
        acc[jj].x = fmaf(av, w.x, acc[jj].x);
        acc[jj].y = fmaf(av, w.y, acc[jj].y);
        acc[jj].z = fmaf(av, w.z, acc[jj].z);
        acc[jj].w = fmaf(av, w.w, acc[jj].w);
      }
    }
  }
  float4 b1v = *(const float4*)&b1[d4];
  __syncthreads();
  #pragma unroll
  for (int jj = 0; jj < 8; ++jj) {
    float4 v = acc[jj];
    v.x = gelu_exact(v.x + b1v.x);
    v.y = gelu_exact(v.y + b1v.y);
    v.z = gelu_exact(v.z + b1v.z);
    v.w = gelu_exact(v.w + b1v.w);
    *(float4*)&s_az[(j8 + jj) * 260 + d4] = v;
  }
  {
    const float4* w2s = (const float4*)W2;
    float4* wdst = (float4*)s_w;
    for (int i = t; i < 2048; i += 256) wdst[i] = w2s[i];
  }
  __syncthreads();
  int j = t >> 3, p4 = (t & 7) * 4;
  float4 o = make_float4(0.f, 0.f, 0.f, 0.f);
  for (int dd = 0; dd < 256; ++dd) {
    float zv = s_az[j * 260 + dd];
    float4 w = *(float4*)&s_w[dd * 32 + p4];
    o.x = fmaf(zv, w.x, o.x);
    o.y = fmaf(zv, w.y, o.y);
    o.z = fmaf(zv, w.z, o.z);
    o.w = fmaf(zv, w.w, o.w);
  }
  float4 b2v = *(const float4*)&b2[p4];
  o.x += b2v.x; o.y += b2v.y; o.z += b2v.z; o.w += b2v.w;
  *(float4*)&out[(size_t)(tok0 + j) * 32 + p4] = o;
}

extern "C" void kernel_launch(void* const* d_in, const int* in_sizes, int n_in,
                              void* d_out, int out_size, void* d_ws, size_t ws_size,
                              hipStream_t stream) {
  const float* y    = (const float*)d_in[0];
  const float* Win  = (const float*)d_in[1];
  const float* bin_ = (const float*)d_in[2];
  const float* ng   = (const float*)d_in[3];
  const float* nb   = (const float*)d_in[4];
  const float* A    = (const float*)d_in[5];
  const float* WB   = (const float*)d_in[6];
  const float* WC   = (const float*)d_in[7];
  const float* qd   = (const float*)d_in[8];
  const float* pd   = (const float*)d_in[9];
  const float* nfg  = (const float*)d_in[10];
  const float* nfb  = (const float*)d_in[11];
  const float* W1   = (const float*)d_in[12];
  const float* b1   = (const float*)d_in[13];
  const float* W2   = (const float*)d_in[14];
  const float* b2   = (const float*)d_in[15];

  float* ws = (float*)d_ws;
  float* hnbuf = ws;                          // NTOK*D; hn -> (in-place) hn2
  float* delta = ws + 4194304;                // NTOK
  float* Bm    = delta + NTOK;                // NTOK*NX
  float* Cm    = Bm + NTOK * NX;              // NTOK*NX
  float* muv   = Cm + NTOK * NX;              // NTOK
  float* irsv  = muv + NTOK;                  // NTOK
  float* Tbuf  = irsv + NTOK;                 // NBATCH*NCH = 512
  float* At    = Tbuf + NBATCH * NCH;         // 4096
  float* Wbct  = At + D * NX;                 // 8192
  float* EX    = Wbct + D * 32;               // NBATCH*NCH*D*NX = 2M floats

  k0_prep<<<48, 256, 0, stream>>>(A, WB, WC, At, Wbct);
  k1_front<<<NTOK / 32, 256, 0, stream>>>(y, Win, bin_, ng, nb, Wbct, qd, pd,
                                          hnbuf, delta, Bm, Cm, muv, irsv);
  k2a_local<<<NBATCH * NCH, 256, 0, stream>>>(hnbuf, delta, Bm, At, EX, Tbuf);
  k2b_chunkscan<<<NBATCH * 16, 256, 0, stream>>>(At, Tbuf, EX);
  k2c_scan2<<<NBATCH * NCH, 256, 0, stream>>>(hnbuf, delta, Bm, Cm, At, EX,
                                              muv, irsv, ng, nb, nfg, nfb,
                                              hnbuf);
  k3b_mlp<<<NTOK / 32, 256, 0, stream>>>(hnbuf, W1, b1, W2, b2, (float*)d_out);
}

// Round 11
// 246.185 us; speedup vs baseline: 1.1130x; 1.0191x over previous
//
#include <hip/hip_runtime.h>
#include <math.h>

#define D 256
#define NX 16
#define L 2048
#define NBATCH 8
#define NTOK (NBATCH * L)
#define CL 32
#define NCH (L / CL)  // 64
#define LOG2E 1.44269504088896340736f

// ---------------- K0: At[n][d] = A[d][n]*LOG2E ; Wbct[d][c] = [WB;WC]^T -----
__global__ __launch_bounds__(256) void k0_prep(const float* __restrict__ A,
                                               const float* __restrict__ WB,
                                               const float* __restrict__ WC,
                                               float* __restrict__ At,
                                               float* __restrict__ Wbct) {
  int i = blockIdx.x * 256 + threadIdx.x;  // 12288 total
  if (i < 4096) {
    int d = i >> 4, n = i & 15;
    At[n * D + d] = A[i] * LOG2E;
  } else {
    int j = i - 4096;  // 8192
    int d = j >> 5, c = j & 31;
    Wbct[j] = (c < 16) ? WB[c * D + d] : WC[(c - 16) * D + d];
  }
}

// ---------------- K1a: front end + LOCAL CHUNK SCAN fused -------------------
// Block = one 32-token chunk. Phase A: h=y@Win+bin, LN, delta (hn,delta in
// LDS+global). Phase C: [Bm|Cm] = hn@Wbct (sB kept in LDS). Scan phase:
// thread=d, x[16] in regs from zero state -> EX end states + T totals.
__global__ __launch_bounds__(256) void k1a_front_scan(
    const float* __restrict__ y, const float* __restrict__ Win,
    const float* __restrict__ bin_, const float* __restrict__ ng,
    const float* __restrict__ nb, const float* __restrict__ Wbct,
    const float* __restrict__ qd, const float* __restrict__ pd,
    const float* __restrict__ At,
    float* __restrict__ hn, float* __restrict__ delta,
    float* __restrict__ Bm, float* __restrict__ Cm,
    float* __restrict__ muv, float* __restrict__ irsv,
    float* __restrict__ EX, float* __restrict__ T) {
  __shared__ float sy[32][32];
  __shared__ float sh[32][260];   // hn tile, pitch 260
  __shared__ float sB[32][NX];
  __shared__ float sdelta[32];
  int t = threadIdx.x;
  int tok0 = blockIdx.x * 32;     // blockIdx.x == global chunk index b*NCH+ch
  {
    const float4* src = (const float4*)(y + (size_t)tok0 * 32);
    ((float4*)sy)[t] = src[t];
  }
  __syncthreads();
  int dcol = t & 63;
  int jrow = t >> 6;
  int d4 = dcol * 4;
  float4 bv = ((const float4*)bin_)[dcol];
  float4 acc[8];
  #pragma unroll
  for (int jj = 0; jj < 8; ++jj) acc[jj] = bv;
  const float4* Win4 = (const float4*)Win;
  #pragma unroll
  for (int k = 0; k < 32; ++k) {
    float4 wv = Win4[k * 64 + dcol];
    #pragma unroll
    for (int jj = 0; jj < 8; ++jj) {
      float av = sy[jrow * 8 + jj][k];
      acc[jj].x = fmaf(av, wv.x, acc[jj].x);
      acc[jj].y = fmaf(av, wv.y, acc[jj].y);
      acc[jj].z = fmaf(av, wv.z, acc[jj].z);
      acc[jj].w = fmaf(av, wv.w, acc[jj].w);
    }
  }
  float4 g4 = ((const float4*)ng)[dcol];
  float4 nb4 = ((const float4*)nb)[dcol];
  float4 q4 = ((const float4*)qd)[dcol];
  float pd0 = pd[0];
  #pragma unroll
  for (int jj = 0; jj < 8; ++jj) {
    int j = jrow * 8 + jj;
    int tok = tok0 + j;
    float4 a = acc[jj];
    float s1 = a.x + a.y + a.z + a.w;
    float s2 = a.x * a.x + a.y * a.y + a.z * a.z + a.w * a.w;
    #pragma unroll
    for (int off = 1; off < 64; off <<= 1) {
      s1 += __shfl_xor(s1, off);
      s2 += __shfl_xor(s2, off);
    }
    float mu = s1 * (1.f / D);
    float var = s2 * (1.f / D) - mu * mu;
    float rstd = rsqrtf(var + 1e-5f);
    if (dcol == 0) { muv[tok] = mu; irsv[tok] = sqrtf(var + 1e-5f); }
    float4 v4;
    v4.x = (a.x - mu) * rstd * g4.x + nb4.x;
    v4.y = (a.y - mu) * rstd * g4.y + nb4.y;
    v4.z = (a.z - mu) * rstd * g4.z + nb4.z;
    v4.w = (a.w - mu) * rstd * g4.w + nb4.w;
    ((float4*)(hn + (size_t)tok * D))[dcol] = v4;
    *(float4*)&sh[j][d4] = v4;
    float dd = v4.x * q4.x + v4.y * q4.y + v4.z * q4.z + v4.w * q4.w;
    #pragma unroll
    for (int off = 1; off < 64; off <<= 1) dd += __shfl_xor(dd, off);
    if (dcol == 0) {
      float xx = pd0 + dd;
      float dv = (xx > 20.f) ? xx : log1pf(expf(xx));
      delta[tok] = dv;
      sdelta[j] = dv;
    }
  }
  __syncthreads();
  // chunk delta total (wave 0, lanes 0..31)
  if (t < 32) {
    float v = sdelta[t];
    #pragma unroll
    for (int off = 1; off < 32; off <<= 1) v += __shfl_xor(v, off);
    if (t == 0) T[blockIdx.x] = v;
  }
  // Phase C: [Bm|Cm] = sh @ Wbct; keep B columns in sB for the scan
  int col4 = t & 7;
  int j = t >> 3;
  const float4* W4 = (const float4*)Wbct;
  float4 o = make_float4(0.f, 0.f, 0.f, 0.f);
  #pragma unroll 8
  for (int d = 0; d < 256; ++d) {
    float av = sh[j][d];
    float4 w = W4[d * 8 + col4];
    o.x = fmaf(av, w.x, o.x);
    o.y = fmaf(av, w.y, o.y);
    o.z = fmaf(av, w.z, o.z);
    o.w = fmaf(av, w.w, o.w);
  }
  int tokj = tok0 + j;
  if (col4 < 4) {
    ((float4*)(Bm + (size_t)tokj * NX))[col4] = o;
    *(float4*)&sB[j][col4 * 4] = o;
  } else {
    ((float4*)(Cm + (size_t)tokj * NX))[col4 - 4] = o;
  }
  __syncthreads();
  // Scan phase: thread = d, state x[16] in regs, zero init
  float a16[16];
  #pragma unroll
  for (int n = 0; n < 16; ++n) a16[n] = At[n * D + t];
  float x16[16];
  #pragma unroll
  for (int n = 0; n < 16; ++n) x16[n] = 0.f;
  for (int lo = 0; lo < CL; ++lo) {
    float dlt = sdelta[lo];
    float du = dlt * sh[lo][t];
    #pragma unroll
    for (int n = 0; n < 16; ++n)
      x16[n] = fmaf(exp2f(dlt * a16[n]), x16[n], du * sB[lo][n]);
  }
  size_t exbase = (size_t)blockIdx.x * (NX * D) + t;
  #pragma unroll
  for (int n = 0; n < 16; ++n) EX[exbase + n * D] = x16[n];
}

// ---------------- K2b: chunk-level scan, in-place E -> X, prefetch ---------
__global__ __launch_bounds__(256) void k2b_chunkscan(
    const float* __restrict__ At, const float* __restrict__ T,
    float* __restrict__ EX) {
  __shared__ float sT[NCH];
  int b = blockIdx.x >> 4;
  int rem = ((blockIdx.x & 15) << 8) | threadIdx.x;  // n*D + d
  if (threadIdx.x < NCH) sT[threadIdx.x] = T[b * NCH + threadIdx.x];
  __syncthreads();
  float A2 = At[rem];  // already *LOG2E
  size_t base = ((size_t)b << 18) + rem;
  float eq[4];
  #pragma unroll
  for (int j = 0; j < 4; ++j) eq[j] = EX[base + ((size_t)j << 12)];
  float x = 0.f;
  #pragma unroll 4
  for (int c = 0; c < NCH; ++c) {
    float e = eq[c & 3];
    if (c + 4 < NCH) eq[c & 3] = EX[base + ((size_t)(c + 4) << 12)];
    EX[base + ((size_t)c << 12)] = x;
    x = fmaf(exp2f(sT[c] * A2), x, e);
  }
}

__device__ __forceinline__ float gelu_exact(float x) {
  return 0.5f * x * (1.f + erff(x * 0.70710678118654752440f));
}

// ---------------- K2cd: fixup scan + h recon + LN2 + MLP fused --------------
// Block = one 32-token chunk (== MLP tile). Scan phase (thread=d) writes final
// y into s_az (pitch 260); LN2 normalizes in place; MLP runs on it (r6 k3b).
__global__ __launch_bounds__(256) void k2cd_scan_mlp(
    const float* __restrict__ hn, const float* __restrict__ delta,
    const float* __restrict__ Bm, const float* __restrict__ Cm,
    const float* __restrict__ At, const float* __restrict__ EX,
    const float* __restrict__ muv, const float* __restrict__ irsv,
    const float* __restrict__ ng, const float* __restrict__ nb,
    const float* __restrict__ nfg, const float* __restrict__ nfb,
    const float* __restrict__ W1, const float* __restrict__ b1,
    const float* __restrict__ W2, const float* __restrict__ b2,
    float* __restrict__ out) {
  __shared__ float s_az[32 * 260];  // y -> hn2 (a-tile) -> z, pitch 260
  __shared__ float s_w[32 * 256];   // W1 k-tiles, then W2
  __shared__ float sB[32][NX];
  __shared__ float sC[32][NX];
  __shared__ float sdelta[32];
  __shared__ float smu[32];
  __shared__ float sirs[32];
  int t = threadIdx.x;
  int tok0 = blockIdx.x * 32;  // blockIdx.x == global chunk index
  size_t tokbase = (size_t)tok0;
  if (t < 32) {
    sdelta[t] = delta[tokbase + t];
    smu[t] = muv[tokbase + t];
    sirs[t] = irsv[tokbase + t];
  }
  for (int i = t; i < 32 * NX; i += 256) {
    ((float*)sB)[i] = Bm[tokbase * NX + i];
    ((float*)sC)[i] = Cm[tokbase * NX + i];
  }
  float a16[16], x16[16];
  size_t exbase = (size_t)blockIdx.x * (NX * D) + t;
  #pragma unroll
  for (int n = 0; n < 16; ++n) {
    a16[n] = At[n * D + t];
    x16[n] = EX[exbase + n * D];
  }
  float nb_d = nb[t];
  float invg = 1.0f / ng[t];
  __syncthreads();
  // scan with true entering state; hn read straight from global (used once)
  for (int lo = 0; lo < CL; ++lo) {
    float hv = hn[(tokbase + lo) * D + t];  // coalesced 1 KB/wave
    float dlt = sdelta[lo];
    float du = dlt * hv;
    float p = 0.f;
    #pragma unroll
    for (int n = 0; n < 16; ++n) {
      x16[n] = fmaf(exp2f(dlt * a16[n]), x16[n], du * sB[lo][n]);
      p = fmaf(x16[n], sC[lo][n], p);
    }
    float h = fmaf((hv - nb_d) * invg, sirs[lo], smu[lo]);
    s_az[lo * 260 + t] = h + p;  // final pre-LN2 value
  }
  __syncthreads();
  // LN2 in place (wave w owns tokens w*8..+7)
  int dcol = t & 63, jrow = t >> 6;
  int d4 = dcol * 4, j8 = jrow * 8;
  {
    float4 g4 = ((const float4*)nfg)[dcol];
    float4 b4 = ((const float4*)nfb)[dcol];
    for (int jj = 0; jj < 8; ++jj) {
      int lo = j8 + jj;
      float4 v = *(float4*)&s_az[lo * 260 + d4];
      float s1 = v.x + v.y + v.z + v.w;
      float s2 = v.x * v.x + v.y * v.y + v.z * v.z + v.w * v.w;
      #pragma unroll
      for (int off = 1; off < 64; off <<= 1) {
        s1 += __shfl_xor(s1, off);
        s2 += __shfl_xor(s2, off);
      }
      float mu2 = s1 * (1.f / D);
      float var2 = s2 * (1.f / D) - mu2 * mu2;
      float rstd2 = rsqrtf(var2 + 1e-5f);
      float4 o;
      o.x = (v.x - mu2) * rstd2 * g4.x + b4.x;
      o.y = (v.y - mu2) * rstd2 * g4.y + b4.y;
      o.z = (v.z - mu2) * rstd2 * g4.z + b4.z;
      o.w = (v.w - mu2) * rstd2 * g4.w + b4.w;
      *(float4*)&s_az[lo * 260 + d4] = o;  // in-place, same row
    }
  }
  // MLP (r6 k3b structure; a-tile at pitch 260)
  float4 acc[8];
  #pragma unroll
  for (int jj = 0; jj < 8; ++jj) acc[jj] = make_float4(0.f, 0.f, 0.f, 0.f);
  for (int kb = 0; kb < 256; kb += 32) {
    __syncthreads();  // prior tile's reads done (first: LN2 writes visible)
    {
      const float4* wsrc = (const float4*)(W1 + kb * D);
      float4* wdst = (float4*)s_w;
      for (int i = t; i < 2048; i += 256) wdst[i] = wsrc[i];
    }
    __syncthreads();
    #pragma unroll 8
    for (int k = 0; k < 32; ++k) {
      float4 w = *(float4*)&s_w[k * D + d4];
      #pragma unroll
      for (int jj = 0; jj < 8; ++jj) {
        float av = s_az[(j8 + jj) * 260 + kb + k];  // wave-uniform broadcast
        acc[jj].x = fmaf(av, w.x, acc[jj].x);
        acc[jj].y = fmaf(av, w.y, acc[jj].y);
        acc[jj].z = fmaf(av, w.z, acc[jj].z);
        acc[jj].w = fmaf(av, w.w, acc[jj].w);
      }
    }
  }
  float4 b1v = *(const float4*)&b1[d4];
  __syncthreads();  // all a-reads done before z overwrites
  #pragma unroll
  for (int jj = 0; jj < 8; ++jj) {
    float4 v = acc[jj];
    v.x = gelu_exact(v.x + b1v.x);
    v.y = gelu_exact(v.y + b1v.y);
    v.z = gelu_exact(v.z + b1v.z);
    v.w = gelu_exact(v.w + b1v.w);
    *(float4*)&s_az[(j8 + jj) * 260 + d4] = v;  // z, pitch 260
  }
  {
    const float4* w2s = (const float4*)W2;
    float4* wdst = (float4*)s_w;
    for (int i = t; i < 2048; i += 256) wdst[i] = w2s[i];
  }
  __syncthreads();
  int j = t >> 3, p4 = (t & 7) * 4;
  float4 o = make_float4(0.f, 0.f, 0.f, 0.f);
  for (int dd = 0; dd < 256; ++dd) {
    float zv = s_az[j * 260 + dd];
    float4 w = *(float4*)&s_w[dd * 32 + p4];
    o.x = fmaf(zv, w.x, o.x);
    o.y = fmaf(zv, w.y, o.y);
    o.z = fmaf(zv, w.z, o.z);
    o.w = fmaf(zv, w.w, o.w);
  }
  float4 b2v = *(const float4*)&b2[p4];
  o.x += b2v.x; o.y += b2v.y; o.z += b2v.z; o.w += b2v.w;
  *(float4*)&out[(size_t)(tok0 + j) * 32 + p4] = o;
}

extern "C" void kernel_launch(void* const* d_in, const int* in_sizes, int n_in,
                              void* d_out, int out_size, void* d_ws, size_t ws_size,
                              hipStream_t stream) {
  const float* y    = (const float*)d_in[0];
  const float* Win  = (const float*)d_in[1];
  const float* bin_ = (const float*)d_in[2];
  const float* ng   = (const float*)d_in[3];
  const float* nb   = (const float*)d_in[4];
  const float* A    = (const float*)d_in[5];
  const float* WB   = (const float*)d_in[6];
  const float* WC   = (const float*)d_in[7];
  const float* qd   = (const float*)d_in[8];
  const float* pd   = (const float*)d_in[9];
  const float* nfg  = (const float*)d_in[10];
  const float* nfb  = (const float*)d_in[11];
  const float* W1   = (const float*)d_in[12];
  const float* b1   = (const float*)d_in[13];
  const float* W2   = (const float*)d_in[14];
  const float* b2   = (const float*)d_in[15];

  float* ws = (float*)d_ws;
  float* hnbuf = ws;                          // NTOK*D
  float* delta = ws + 4194304;                // NTOK
  float* Bm    = delta + NTOK;                // NTOK*NX
  float* Cm    = Bm + NTOK * NX;              // NTOK*NX
  float* muv   = Cm + NTOK * NX;              // NTOK
  float* irsv  = muv + NTOK;                  // NTOK
  float* Tbuf  = irsv + NTOK;                 // 512
  float* At    = Tbuf + NBATCH * NCH;         // 4096
  float* Wbct  = At + D * NX;                 // 8192
  float* EX    = Wbct + D * 32;               // 512*4096 = 2M floats

  k0_prep<<<48, 256, 0, stream>>>(A, WB, WC, At, Wbct);
  k1a_front_scan<<<NTOK / 32, 256, 0, stream>>>(y, Win, bin_, ng, nb, Wbct,
                                                qd, pd, At, hnbuf, delta, Bm,
                                                Cm, muv, irsv, EX, Tbuf);
  k2b_chunkscan<<<NBATCH * 16, 256, 0, stream>>>(At, Tbuf, EX);
  k2cd_scan_mlp<<<NTOK / 32, 256, 0, stream>>>(hnbuf, delta, Bm, Cm, At, EX,
                                               muv, irsv, ng, nb, nfg, nfb,
                                               W1, b1, W2, b2, (float*)d_out);
}